// Round 3
// baseline (1560.122 us; speedup 1.0000x reference)
//
#include <hip/hip_runtime.h>
#include <hip/hip_bf16.h>
#include <math.h>

// Pattern-aware MoE, MI355X. Sparse top-2 dispatch with bf16 MFMA grouped GEMMs.
// B=8 S=4096 D=512 H=2048 E=8 P=16 K=2.
// R3: sorted pair lists + block-table grouped single-launch GEMMs (split-H),
//     LDS double-buffer with raw vmcnt(N)+s_barrier pipeline (AITER-style).

#define B_ 8
#define S_ 4096
#define D_ 512
#define H_ 2048
#define HS_ 1024            // split-H chunk (2 passes)
#define E_ 8
#define P_ 16
#define NTOK (B_ * S_)      // 32768
#define NPAIR (NTOK * 2)    // 65536
#define NRBLK (NTOK / 32)   // 1024 router blocks
#define TABN 520            // max m-blocks: 512 + 8 partials

typedef __bf16 bf16;
typedef __bf16 bf16x8 __attribute__((ext_vector_type(8)));
typedef float f32x4 __attribute__((ext_vector_type(4)));

// ---- workspace layout (bytes) ----
#define OFF_PROB 0                       // float[8]
#define OFF_Z 32                         // float
#define OFF_GATES 256                    // float[NPAIR]
#define OFF_TAB (OFF_GATES + NPAIR * 4)  // int4[TABN] = 8320
#define OFF_HIST (OFF_TAB + 8448)        // int[NRBLK][8] = 32 KB
#define OFF_OBASE (OFF_HIST + 32768)     // int[NRBLK][8] = 32 KB
#define OFF_STAGE (OFF_OBASE + 32768)    // int[E][NRBLK][64] = 2 MB
#define OFF_LIST (OFF_STAGE + 2097152)   // int[NPAIR] sorted-concat
#define OFF_XBF (OFF_LIST + NPAIR * 4)
#define OFF_W1T (OFF_XBF + (size_t)NTOK * D_ * 2)
#define OFF_W3T (OFF_W1T + (size_t)E_ * H_ * D_ * 2)
#define OFF_W2T (OFF_W3T + (size_t)E_ * H_ * D_ * 2)
#define OFF_HBUF (OFF_W2T + (size_t)E_ * D_ * H_ * 2)
#define WS_NEEDED (OFF_HBUF + (size_t)(NPAIR + 128) * HS_ * 2)  // ~222 MB

#define GL16(g, l)                                                                        \
  __builtin_amdgcn_global_load_lds((const __attribute__((address_space(1))) unsigned int*)(g), \
                                   (__attribute__((address_space(3))) unsigned int*)(l), 16, 0, 0)

// ============================ router =====================================
// 1 block = 32 tokens. Logits via pair-per-lane LDS dot products; top-2 +
// softmax per octet; per-block staged expert lists (sorted later).
__global__ __launch_bounds__(256) void router_kernel(
    const float* __restrict__ x, const int* __restrict__ pids,
    const float* __restrict__ Wr, const float* __restrict__ Wp,
    bf16* __restrict__ xbf, float* __restrict__ gates, int* __restrict__ stageL,
    int* __restrict__ hist, float* __restrict__ probSum, float* __restrict__ zSum) {
  __shared__ float xs[32 * 516];
  __shared__ float wr_s[E_ * 516];
  __shared__ float wp_s[E_];
  __shared__ float probAcc[E_];
  __shared__ float zAcc;
  __shared__ int lcnt[E_];
  __shared__ float lg_s[32][E_ + 1];

  const int tid = threadIdx.x;
  const int tok0 = blockIdx.x * 32;

#pragma unroll
  for (int rep = 0; rep < (D_ * E_) / 256; ++rep) {
    int flat = rep * 256 + tid;  // Wr is [D][E]
    wr_s[(flat & 7) * 516 + (flat >> 3)] = Wr[flat];
  }
  if (tid < E_) {
    wp_s[tid] = Wp[pids[tok0 >> 12] * E_ + tid];
    probAcc[tid] = 0.f;
    lcnt[tid] = 0;
  }
  if (tid == 0) zAcc = 0.f;

  const float4* x4 = (const float4*)(x + (size_t)tok0 * D_);
#pragma unroll
  for (int rep = 0; rep < 16; ++rep) {
    int idx = rep * 256 + tid;
    float4 v = x4[idx];
    int t = idx >> 7;
    int d = (idx & 127) * 4;
    *(float4*)(xs + t * 516 + d) = v;
    union { unsigned short u[4]; uint2 qq; } pk;
    pk.u[0] = __builtin_bit_cast(unsigned short, (bf16)v.x);
    pk.u[1] = __builtin_bit_cast(unsigned short, (bf16)v.y);
    pk.u[2] = __builtin_bit_cast(unsigned short, (bf16)v.z);
    pk.u[3] = __builtin_bit_cast(unsigned short, (bf16)v.w);
    *(uint2*)(xbf + (size_t)tok0 * D_ + (size_t)idx * 4) = pk.qq;
  }
  __syncthreads();

  const int t = tid >> 3, e = tid & 7;
  const int lane = tid & 63;
  {
    float a0 = 0.f, a1 = 0.f, a2 = 0.f, a3 = 0.f;
    const float* xr = xs + t * 516;
    const float* wr = wr_s + e * 516;
#pragma unroll 8
    for (int d = 0; d < D_; d += 4) {
      float4 xv = *(const float4*)(xr + d);
      float4 wv = *(const float4*)(wr + d);
      a0 += xv.x * wv.x;
      a1 += xv.y * wv.y;
      a2 += xv.z * wv.z;
      a3 += xv.w * wv.w;
    }
    lg_s[t][e] = (a0 + a1) + (a2 + a3) + wp_s[e];
  }
  __syncthreads();

  float v[E_];
#pragma unroll
  for (int k = 0; k < E_; ++k) v[k] = lg_s[t][k];
  const float lg = v[e];
  float m = v[0];
#pragma unroll
  for (int k = 1; k < E_; ++k) m = fmaxf(m, v[k]);
  float s = 0.f;
#pragma unroll
  for (int k = 0; k < E_; ++k) s += expf(v[k] - m);
  float prob = expf(lg - m) / s;
  float z = lg * lg;
  int i1 = 0;
  float v1 = v[0];
#pragma unroll
  for (int k = 1; k < E_; ++k)
    if (v[k] > v1) { v1 = v[k]; i1 = k; }
  int i2 = -1;
  float v2 = -1e30f;
#pragma unroll
  for (int k = 0; k < E_; ++k)
    if (k != i1 && v[k] > v2) { v2 = v[k]; i2 = k; }

  float p = prob;
  p += __shfl_xor(p, 8);
  p += __shfl_xor(p, 16);
  p += __shfl_xor(p, 32);
  float zz = z;
#pragma unroll
  for (int off = 1; off < 64; off <<= 1) zz += __shfl_xor(zz, off);
  if (lane < 8) atomicAdd(&probAcc[e], p);
  if (lane == 0) atomicAdd(&zAcc, zz);

  int r = (e == i1) ? 0 : ((e == i2) ? 1 : -1);
  if (r >= 0) {
    float ex = expf(v2 - v1);
    float g = (r == 0) ? 1.f / (1.f + ex) : ex / (1.f + ex);
    gates[(tok0 + t) * 2 + r] = g;
    int pos = atomicAdd(&lcnt[e], 1);
    stageL[(e * NRBLK + blockIdx.x) * 64 + pos] = (tok0 + t) * 2 + r;
  }
  __syncthreads();
  if (tid < E_) {
    hist[blockIdx.x * E_ + tid] = lcnt[tid];
    atomicAdd(&probSum[tid], probAcc[tid]);
  } else if (tid == 8) {
    atomicAdd(zSum, zAcc);
  }
}

// ==================== scan: offsets + block table ========================
__global__ __launch_bounds__(256) void scan_kernel(const int* __restrict__ hist,
                                                   int* __restrict__ obase, int4* __restrict__ tab) {
  __shared__ int baseE[E_], cntE[E_];
  const int tid = threadIdx.x;
  const int g = tid >> 5, l = tid & 31;  // group g = expert, 32 lanes scan 1024 blocks
  int sum = 0;
  for (int j = 0; j < 32; ++j) sum += hist[(l * 32 + j) * E_ + g];
  int inc = sum;
#pragma unroll
  for (int d = 1; d < 32; d <<= 1) {
    int tval = __shfl_up(inc, d, 32);
    if (l >= d) inc += tval;
  }
  const int excl = inc - sum;
  if (l == 31) cntE[g] = inc;
  __syncthreads();
  if (tid == 0) {
    int b = 0;
    for (int e = 0; e < E_; ++e) {
      baseE[e] = b;
      b += cntE[e];
    }
  }
  __syncthreads();
  int run = baseE[g] + excl;
  for (int j = 0; j < 32; ++j) {
    int b = l * 32 + j;
    int h = hist[b * E_ + g];
    obase[b * E_ + g] = run;
    run += h;
  }
  if (tid == 0) {
    int idx = 0;
    for (int e = 0; e < E_; ++e) {
      int bse = baseE[e], c = cntE[e];
      for (int j = 0; j * 128 < c; ++j) tab[idx++] = make_int4(bse + j * 128, bse + c, e, 0);
    }
    for (; idx < TABN; ++idx) tab[idx] = make_int4(-1, 0, 0, 0);
  }
}

// ===================== scatter staged lists (sorted) =====================
__global__ __launch_bounds__(256) void scatter_kernel(const int* __restrict__ hist,
                                                      const int* __restrict__ obase,
                                                      const int* __restrict__ stageL,
                                                      int* __restrict__ lists) {
  const int b = blockIdx.x, tid = threadIdx.x;
  for (int idx = tid; idx < E_ * 64; idx += 256) {
    int e = idx >> 6, i = idx & 63;
    if (i < hist[b * E_ + e]) lists[obase[b * E_ + e] + i] = stageL[(e * NRBLK + b) * 64 + i];
  }
}

// ======================= transpose + fp32->bf16 ==========================
__global__ __launch_bounds__(256) void transpose_convert(const float* __restrict__ in,
                                                         bf16* __restrict__ out, int R, int C) {
  const int e = blockIdx.z;
  const int r0 = blockIdx.y * 64, c0 = blockIdx.x * 64;
  in += (size_t)e * R * C;
  out += (size_t)e * R * C;
  __shared__ unsigned int lt[64 * 33];
  const int tid = threadIdx.x;
  const int m = tid & 15, q = tid >> 4;
#pragma unroll
  for (int rep = 0; rep < 2; ++rep) {
    int rp = q + rep * 16;
    const float4 a = *(const float4*)(in + (size_t)(r0 + rp * 2) * C + c0 + m * 4);
    const float4 b = *(const float4*)(in + (size_t)(r0 + rp * 2 + 1) * C + c0 + m * 4);
#pragma unroll
    for (int j = 0; j < 4; ++j) {
      unsigned short lo = __builtin_bit_cast(unsigned short, (bf16)((&a.x)[j]));
      unsigned short hi = __builtin_bit_cast(unsigned short, (bf16)((&b.x)[j]));
      lt[(m * 4 + j) * 33 + rp] = (unsigned int)lo | ((unsigned int)hi << 16);
    }
  }
  __syncthreads();
  const int c = tid >> 2, dw0 = (tid & 3) * 8;
  unsigned int vv[8];
#pragma unroll
  for (int j = 0; j < 8; ++j) vv[j] = lt[c * 33 + dw0 + j];
  uint4* dst = (uint4*)(out + (size_t)(c0 + c) * R + r0 + dw0 * 2);
  dst[0] = make_uint4(vv[0], vv[1], vv[2], vv[3]);
  dst[1] = make_uint4(vv[4], vv[5], vv[6], vv[7]);
}

// ============================== GEMM1 ====================================
// h = gate * (X@W1e) * silu(X@W3e) for HS-wide slice; table-driven, dbuf.
__global__ __launch_bounds__(256, 3) void gemm1_kernel(
    const bf16* __restrict__ xbf, const bf16* __restrict__ W1T, const bf16* __restrict__ W3T,
    const int4* __restrict__ tab, const int* __restrict__ lists,
    const float* __restrict__ gates, bf16* __restrict__ hbuf, int ns0) {
  const int4 te = tab[blockIdx.y];
  if (te.x < 0) return;
  const int gS = te.x, gE = te.y, e = te.z;
  const int n0 = blockIdx.x * 128;  // within [0, HS_)
  const bf16* W1e = W1T + ((size_t)e * H_ + ns0 + n0) * D_;
  const bf16* W3e = W3T + ((size_t)e * H_ + ns0 + n0) * D_;

  __shared__ bf16 sA[2][4096], sB1[2][4096], sB3[2][4096];
  __shared__ int stok[128];
  __shared__ float sgate[128];

  const int tid = threadIdx.x;
  if (tid < 128) {
    int gR = gS + tid;
    int pr = (gR < gE) ? lists[gR] : 0;
    stok[tid] = pr >> 1;
    sgate[tid] = (gR < gE) ? gates[pr] : 0.f;
  }
  __syncthreads();

  const int wave = tid >> 6, lane = tid & 63;
  const int rsub = lane >> 2, kq = lane & 3;
  const int rA0 = wave * 16 + rsub, rA1 = 64 + wave * 16 + rsub;
  const bf16* aP0 = xbf + (size_t)stok[rA0] * D_ + kq * 8;
  const bf16* aP1 = xbf + (size_t)stok[rA1] * D_ + kq * 8;
  const bf16* b1P0 = W1e + (size_t)rA0 * D_ + kq * 8;
  const bf16* b1P1 = W1e + (size_t)rA1 * D_ + kq * 8;
  const bf16* b3P0 = W3e + (size_t)rA0 * D_ + kq * 8;
  const bf16* b3P1 = W3e + (size_t)rA1 * D_ + kq * 8;
  const int l0 = wave * 512, l1 = (wave + 4) * 512;

  const int wm = wave >> 1, wn = wave & 1;
  const int lm = lane & 15, q = lane >> 4;
  const int rdOff = (wm * 64 + lm) * 32 + q * 8;
  const int rdOffB = (wn * 64 + lm) * 32 + q * 8;

  f32x4 acc1[4][4] = {};
  f32x4 acc3[4][4] = {};

  // prologue: tile 0 -> buf 0
  GL16(aP0, &sA[0][l0]);
  GL16(aP1, &sA[0][l1]);
  GL16(b1P0, &sB1[0][l0]);
  GL16(b1P1, &sB1[0][l1]);
  GL16(b3P0, &sB3[0][l0]);
  GL16(b3P1, &sB3[0][l1]);

#pragma unroll
  for (int it = 0; it < 15; ++it) {
    const int cb = it & 1, nb = cb ^ 1;
    const int k0 = (it + 1) * 32;
    GL16(aP0 + k0, &sA[nb][l0]);
    GL16(aP1 + k0, &sA[nb][l1]);
    GL16(b1P0 + k0, &sB1[nb][l0]);
    GL16(b1P1 + k0, &sB1[nb][l1]);
    GL16(b3P0 + k0, &sB3[nb][l0]);
    GL16(b3P1 + k0, &sB3[nb][l1]);
    asm volatile("s_waitcnt vmcnt(6)\n\ts_barrier" ::: "memory");  // own tile-k loads done
    bf16x8 af[4], b1f[4], b3f[4];
#pragma unroll
    for (int i = 0; i < 4; ++i) {
      af[i] = *(const bf16x8*)(&sA[cb][rdOff + i * 512]);
      b1f[i] = *(const bf16x8*)(&sB1[cb][rdOffB + i * 512]);
      b3f[i] = *(const bf16x8*)(&sB3[cb][rdOffB + i * 512]);
    }
#pragma unroll
    for (int mt = 0; mt < 4; ++mt) {
#pragma unroll
      for (int nt = 0; nt < 4; ++nt) {
        acc1[mt][nt] =
            __builtin_amdgcn_mfma_f32_16x16x32_bf16(af[mt], b1f[nt], acc1[mt][nt], 0, 0, 0);
        acc3[mt][nt] =
            __builtin_amdgcn_mfma_f32_16x16x32_bf16(af[mt], b3f[nt], acc3[mt][nt], 0, 0, 0);
      }
    }
    asm volatile("s_waitcnt lgkmcnt(0)\n\ts_barrier" ::: "memory");  // cb consumed
  }
  // peeled last tile (buf 1)
  asm volatile("s_waitcnt vmcnt(0)\n\ts_barrier" ::: "memory");
  {
    bf16x8 af[4], b1f[4], b3f[4];
#pragma unroll
    for (int i = 0; i < 4; ++i) {
      af[i] = *(const bf16x8*)(&sA[1][rdOff + i * 512]);
      b1f[i] = *(const bf16x8*)(&sB1[1][rdOffB + i * 512]);
      b3f[i] = *(const bf16x8*)(&sB3[1][rdOffB + i * 512]);
    }
#pragma unroll
    for (int mt = 0; mt < 4; ++mt) {
#pragma unroll
      for (int nt = 0; nt < 4; ++nt) {
        acc1[mt][nt] =
            __builtin_amdgcn_mfma_f32_16x16x32_bf16(af[mt], b1f[nt], acc1[mt][nt], 0, 0, 0);
        acc3[mt][nt] =
            __builtin_amdgcn_mfma_f32_16x16x32_bf16(af[mt], b3f[nt], acc3[mt][nt], 0, 0, 0);
      }
    }
  }

#pragma unroll
  for (int mt = 0; mt < 4; ++mt) {
#pragma unroll
    for (int nt = 0; nt < 4; ++nt) {
#pragma unroll
      for (int r = 0; r < 4; ++r) {
        int lrow = wm * 64 + mt * 16 + q * 4 + r;  // C/D: row=(lane>>4)*4+reg, col=lane&15
        if (gS + lrow < gE) {
          float v1 = acc1[mt][nt][r];
          float v3 = acc3[mt][nt][r];
          float g = v1 * (v3 / (1.f + __expf(-v3))) * sgate[lrow];
          hbuf[(size_t)(gS + lrow) * HS_ + n0 + wn * 64 + nt * 16 + lm] = (bf16)g;
        }
      }
    }
  }
}

// ============================== GEMM2 ====================================
// y += hact-slice @ W2e-slice; contiguous hbuf rows; atomicAdd scatter.
__global__ __launch_bounds__(256, 4) void gemm2_kernel(
    const bf16* __restrict__ hbuf, const bf16* __restrict__ W2T, const int4* __restrict__ tab,
    const int* __restrict__ lists, float* __restrict__ y, int ns0) {
  const int4 te = tab[blockIdx.y];
  if (te.x < 0) return;
  const int gS = te.x, gE = te.y, e = te.z;
  const int n0 = blockIdx.x * 128;  // over D
  const bf16* W2e = W2T + (size_t)e * D_ * H_;

  __shared__ bf16 sA[2][4096], sB[2][4096];
  __shared__ int stok[128];

  const int tid = threadIdx.x;
  if (tid < 128) {
    int gR = gS + tid;
    stok[tid] = (gR < gE) ? (lists[gR] >> 1) : 0;
  }
  __syncthreads();

  const int wave = tid >> 6, lane = tid & 63;
  const int rsub = lane >> 2, kq = lane & 3;
  const int rA0 = wave * 16 + rsub, rA1 = 64 + wave * 16 + rsub;
  const bf16* aP0 = hbuf + (size_t)(gS + rA0) * HS_ + kq * 8;
  const bf16* aP1 = hbuf + (size_t)(gS + rA1) * HS_ + kq * 8;
  const bf16* bP0 = W2e + (size_t)(n0 + rA0) * H_ + ns0 + kq * 8;
  const bf16* bP1 = W2e + (size_t)(n0 + rA1) * H_ + ns0 + kq * 8;
  const int l0 = wave * 512, l1 = (wave + 4) * 512;

  const int wm = wave >> 1, wn = wave & 1;
  const int lm = lane & 15, q = lane >> 4;
  const int rdOff = (wm * 64 + lm) * 32 + q * 8;
  const int rdOffB = (wn * 64 + lm) * 32 + q * 8;

  f32x4 acc[4][4] = {};

  GL16(aP0, &sA[0][l0]);
  GL16(aP1, &sA[0][l1]);
  GL16(bP0, &sB[0][l0]);
  GL16(bP1, &sB[0][l1]);

#pragma unroll
  for (int it = 0; it < 31; ++it) {
    const int cb = it & 1, nb = cb ^ 1;
    const int k0 = (it + 1) * 32;
    GL16(aP0 + k0, &sA[nb][l0]);
    GL16(aP1 + k0, &sA[nb][l1]);
    GL16(bP0 + k0, &sB[nb][l0]);
    GL16(bP1 + k0, &sB[nb][l1]);
    asm volatile("s_waitcnt vmcnt(4)\n\ts_barrier" ::: "memory");
    bf16x8 af[4], bf_[4];
#pragma unroll
    for (int i = 0; i < 4; ++i) {
      af[i] = *(const bf16x8*)(&sA[cb][rdOff + i * 512]);
      bf_[i] = *(const bf16x8*)(&sB[cb][rdOffB + i * 512]);
    }
#pragma unroll
    for (int mt = 0; mt < 4; ++mt) {
#pragma unroll
      for (int nt = 0; nt < 4; ++nt) {
        acc[mt][nt] =
            __builtin_amdgcn_mfma_f32_16x16x32_bf16(af[mt], bf_[nt], acc[mt][nt], 0, 0, 0);
      }
    }
    asm volatile("s_waitcnt lgkmcnt(0)\n\ts_barrier" ::: "memory");
  }
  asm volatile("s_waitcnt vmcnt(0)\n\ts_barrier" ::: "memory");
  {
    bf16x8 af[4], bf_[4];
#pragma unroll
    for (int i = 0; i < 4; ++i) {
      af[i] = *(const bf16x8*)(&sA[1][rdOff + i * 512]);
      bf_[i] = *(const bf16x8*)(&sB[1][rdOffB + i * 512]);
    }
#pragma unroll
    for (int mt = 0; mt < 4; ++mt) {
#pragma unroll
      for (int nt = 0; nt < 4; ++nt) {
        acc[mt][nt] =
            __builtin_amdgcn_mfma_f32_16x16x32_bf16(af[mt], bf_[nt], acc[mt][nt], 0, 0, 0);
      }
    }
  }

#pragma unroll
  for (int mt = 0; mt < 4; ++mt) {
#pragma unroll
    for (int nt = 0; nt < 4; ++nt) {
#pragma unroll
      for (int r = 0; r < 4; ++r) {
        int lrow = wm * 64 + mt * 16 + q * 4 + r;
        if (gS + lrow < gE) {
          atomicAdd(&y[(size_t)stok[lrow] * D_ + n0 + wn * 64 + nt * 16 + lm], acc[mt][nt][r]);
        }
      }
    }
  }
}

// ============================= finalize ==================================
__global__ __launch_bounds__(256) void finalize_kernel(const float* __restrict__ Wp,
                                                       const float* __restrict__ probSum,
                                                       const float* __restrict__ zSum,
                                                       float* __restrict__ out) {
  __shared__ float pn[P_][E_];
  __shared__ float simAcc;
  const int tid = threadIdx.x;
  if (tid == 0) simAcc = 0.f;
  if (tid < P_) {
    float v[E_], m = -1e30f, s = 0.f;
#pragma unroll
    for (int e = 0; e < E_; ++e) {
      v[e] = Wp[tid * E_ + e];
      m = fmaxf(m, v[e]);
    }
#pragma unroll
    for (int e = 0; e < E_; ++e) {
      float ex = expf(v[e] - m);
      pn[tid][e] = ex;
      s += ex;
    }
#pragma unroll
    for (int e = 0; e < E_; ++e) pn[tid][e] /= s;
  }
  __syncthreads();
  {
    int i = tid >> 4, j = tid & 15;
    if (i != j) {
      float d = 0.f;
#pragma unroll
      for (int e = 0; e < E_; ++e) d += pn[i][e] * pn[j][e];
      atomicAdd(&simAcc, d);
    }
  }
  __syncthreads();
  if (tid == 0) {
    out[0] = zSum[0] / (float)(NTOK * E_) * 0.001f;
    float bl = 0.f;
#pragma unroll
    for (int e = 0; e < E_; ++e) {
      float pm = probSum[e] / (float)NTOK - 1.f / (float)E_;
      bl += pm * pm;
    }
    out[1] = bl / (float)E_;
    out[2] = simAcc / (float)(P_ * P_) * 0.1f;
  }
}

// ============================== launch ===================================
extern "C" void kernel_launch(void* const* d_in, const int* in_sizes, int n_in, void* d_out,
                              int out_size, void* d_ws, size_t ws_size, hipStream_t stream) {
  const float* x = (const float*)d_in[0];
  const int* pids = (const int*)d_in[1];
  const float* Wr = (const float*)d_in[2];
  const float* Wp = (const float*)d_in[3];
  const float* W1 = (const float*)d_in[4];
  const float* W2 = (const float*)d_in[5];
  const float* W3 = (const float*)d_in[6];
  float* y = (float*)d_out;

  if (ws_size < WS_NEEDED) return;  // fail loudly rather than corrupt

  char* ws = (char*)d_ws;
  float* probSum = (float*)(ws + OFF_PROB);
  float* zSum = (float*)(ws + OFF_Z);
  float* gates = (float*)(ws + OFF_GATES);
  int4* tab = (int4*)(ws + OFF_TAB);
  int* hist = (int*)(ws + OFF_HIST);
  int* obase = (int*)(ws + OFF_OBASE);
  int* stageL = (int*)(ws + OFF_STAGE);
  int* lists = (int*)(ws + OFF_LIST);
  bf16* xbf = (bf16*)(ws + OFF_XBF);
  bf16* W1T = (bf16*)(ws + OFF_W1T);
  bf16* W3T = (bf16*)(ws + OFF_W3T);
  bf16* W2T = (bf16*)(ws + OFF_W2T);
  bf16* hbuf = (bf16*)(ws + OFF_HBUF);

  hipMemsetAsync(ws, 0, 256, stream);                       // probSum + zSum
  hipMemsetAsync(d_out, 0, (size_t)NTOK * D_ * 4, stream);  // y base for atomic combine

  router_kernel<<<dim3(NRBLK), 256, 0, stream>>>(x, pids, Wr, Wp, xbf, gates, stageL, hist,
                                                 probSum, zSum);
  scan_kernel<<<1, 256, 0, stream>>>(hist, obase, tab);
  scatter_kernel<<<dim3(NRBLK), 256, 0, stream>>>(hist, obase, stageL, lists);
  transpose_convert<<<dim3(H_ / 64, D_ / 64, E_), 256, 0, stream>>>(W1, W1T, D_, H_);
  transpose_convert<<<dim3(H_ / 64, D_ / 64, E_), 256, 0, stream>>>(W3, W3T, D_, H_);
  transpose_convert<<<dim3(D_ / 64, H_ / 64, E_), 256, 0, stream>>>(W2, W2T, H_, D_);

  for (int s = 0; s < 2; ++s) {
    gemm1_kernel<<<dim3(HS_ / 128, TABN), 256, 0, stream>>>(xbf, W1T, W3T, tab, lists, gates,
                                                            hbuf, s * HS_);
    gemm2_kernel<<<dim3(D_ / 128, TABN), 256, 0, stream>>>(hbuf, W2T, tab, lists, y, s * HS_);
  }
  finalize_kernel<<<1, 256, 0, stream>>>(Wp, probSum, zSum, y + (size_t)NTOK * D_);
}